// Round 25
// baseline (28.431 us; speedup 1.0000x reference)
//
#include <hip/hip_runtime.h>

// out[b,o] = sum_h W2[o,h]*leaky(h) + b2[o],  h = W1[o]·x[b] + b1[o]
// leaky(t) = 0.6t + 0.4|t|
//   out[b,o] = 0.6(v[o]·x[b]) + c0[o] + sum_h (0.4 W2[o,h])|h|
// R26 = R25 (stage1 mfma_32x32x16 full-rate w/ b1-as-f32-C; stage2 = 16 f32
// FMAs w/ free |.|; zero cvt in loop; math HW-verified absmax 0.03125) with
// the latency chain broken:
//  - 4 waves/SIMD (256 blk x 1024 thr, R23-verified config) — R25 was
//    latency-serialized at 2 waves/SIMD (~440 cyc/p-iter: ds_read lat ->
//    MFMA lat -> 64 dep FMAs); TLP fills those stalls. (R23's TLP-null was
//    on the legacy-MFMA-pipe-bound R21 structure — different regime.)
//  - p-loop unroll 2: batches two iters' LDS reads, overlaps FMA consume
//    with next iter's loads. Transients 72 + ~40 persistent < 128 cap.

#define H_DIM 512

typedef _Float16 f16x8  __attribute__((ext_vector_type(8)));
typedef __fp16   h16x2  __attribute__((ext_vector_type(2)));   // cvt_pkrtz native
typedef float    f32x4  __attribute__((ext_vector_type(4)));
typedef float    f32x16 __attribute__((ext_vector_type(16)));
typedef int      i32x4  __attribute__((ext_vector_type(4)));

// 256 blocks x 1024 thr (16 waves), 1 block/CU, 4 waves/SIMD.
// o = blk&15, grp = blk>>4 (16). Block: 2048 rows; wave: 128 rows
// (2 halves x 2 tile-pairs of 32).
__global__ __launch_bounds__(1024, 1) void mlp_fused(
    const float* __restrict__ x, const float* __restrict__ W1,
    const float* __restrict__ b1, const float* __restrict__ W2,
    const float* __restrict__ b2, float* __restrict__ out) {
    __shared__ f16x8 sm_a1[1024];     // [p][lane] W1 frags (32x32x16 A) 16 KiB
    __shared__ float sm_b1p[512];     // [p][hi][r] b1 in D-layout        2 KiB
    __shared__ float sm_w2p[512];     // [p][hi][r] 0.4*W2 in D-layout    2 KiB
    __shared__ float redv[1024];      //  4 KiB
    __shared__ float redc[1024];      //  4 KiB
    __shared__ float v_sm[16];
    __shared__ float c_sm;

    const int tid = threadIdx.x;
    const int o   = blockIdx.x & 15;
    const int grp = blockIdx.x >> 4;
    const float* W1o = W1 + (size_t)o * H_DIM * 16;
    const float* W2o = W2 + (size_t)o * H_DIM;
    const float* b1o = b1 + (size_t)o * H_DIM;

    const int lane = tid & 63, w = tid >> 6;
    const int c = lane & 31, hi = lane >> 5;

    // ---- phase A (single pass, 1024 threads) ----
    // A-frags: entry e=[p][lane]: lane l: row=l&31, k=(l>>5)*8+j
    {
        const int e = tid;
        const int l = e & 63, p = e >> 6;
        const float* src = W1o + (size_t)(p * 32 + (l & 31)) * 16 + (l >> 5) * 8;
        const f32x4 a0 = *reinterpret_cast<const f32x4*>(src);
        const f32x4 a1v = *reinterpret_cast<const f32x4*>(src + 4);
        h16x2 q0 = __builtin_amdgcn_cvt_pkrtz(a0[0], a0[1]);
        h16x2 q1 = __builtin_amdgcn_cvt_pkrtz(a0[2], a0[3]);
        h16x2 q2 = __builtin_amdgcn_cvt_pkrtz(a1v[0], a1v[1]);
        h16x2 q3 = __builtin_amdgcn_cvt_pkrtz(a1v[2], a1v[3]);
        i32x4 vi;
        vi[0] = __builtin_bit_cast(int, q0); vi[1] = __builtin_bit_cast(int, q1);
        vi[2] = __builtin_bit_cast(int, q2); vi[3] = __builtin_bit_cast(int, q3);
        sm_a1[e] = __builtin_bit_cast(f16x8, vi);
    }
    // b1/w2 permuted to 32x32 D-layout: entry (p*2+hh)*16+r, h=p*32+R(r,hh)
    if (tid < 512) {
        const int p = tid >> 5, hh = (tid >> 4) & 1, r = tid & 15;
        const int h = p * 32 + (r & 3) + 8 * (r >> 2) + 4 * hh;
        sm_b1p[tid] = b1o[h];
        sm_w2p[tid] = 0.4f * W2o[h];
    }
    // v partials (64 chunks x 8 h) + c0 partials
    {
        const int i = tid & 15, hc = tid >> 4;     // hc in 0..63
        float a = 0.f;
#pragma unroll
        for (int hh = 0; hh < 8; ++hh) {
            const int h = hc * 8 + hh;
            a = fmaf(W2o[h], W1o[(size_t)h * 16 + i], a);
        }
        redv[tid] = a;
        redc[tid] = (tid < 512) ? W2o[tid] * b1o[tid] : 0.f;
    }
    __syncthreads();
    if (tid < 16) {
        float s = 0.f;
#pragma unroll
        for (int k = 0; k < 64; ++k) s += redv[tid + 16 * k];
        v_sm[tid] = 0.6f * s;
    }
    if (tid < 64) {
        float cs = 0.f;
#pragma unroll
        for (int k = 0; k < 16; ++k) cs += redc[tid + 64 * k];
#pragma unroll
        for (int m = 1; m <= 32; m <<= 1) cs += __shfl_xor(cs, m, 64);
        if (tid == 0) c_sm = 0.6f * cs + b2[o];
    }
    __syncthreads();

    // ---- phase B ----
    const float c0 = c_sm;
    const f32x4 vh0 = *reinterpret_cast<const f32x4*>(&v_sm[hi * 8]);
    const f32x4 vh1 = *reinterpret_cast<const f32x4*>(&v_sm[hi * 8 + 4]);

    for (int half = 0; half < 2; ++half) {
        const int rbase = grp * 2048 + half * 1024 + w * 64 + c;

        f16x8 xf0, xf1;
        f32x4 nlv0, nlv1;
#pragma unroll
        for (int tp = 0; tp < 2; ++tp) {
            const float* xp = x + (size_t)(rbase + tp * 32) * 16 + hi * 8;
            const f32x4 x0 = *reinterpret_cast<const f32x4*>(xp);
            const f32x4 x1 = *reinterpret_cast<const f32x4*>(xp + 4);
            const f32x4 nl = x0 * vh0 + x1 * vh1;   // exact-f32 lin half
            h16x2 q0 = __builtin_amdgcn_cvt_pkrtz(x0[0], x0[1]);
            h16x2 q1 = __builtin_amdgcn_cvt_pkrtz(x0[2], x0[3]);
            h16x2 q2 = __builtin_amdgcn_cvt_pkrtz(x1[0], x1[1]);
            h16x2 q3 = __builtin_amdgcn_cvt_pkrtz(x1[2], x1[3]);
            i32x4 xi;
            xi[0] = __builtin_bit_cast(int, q0); xi[1] = __builtin_bit_cast(int, q1);
            xi[2] = __builtin_bit_cast(int, q2); xi[3] = __builtin_bit_cast(int, q3);
            const f16x8 xfv = __builtin_bit_cast(f16x8, xi);
            if (tp == 0) { xf0 = xfv; nlv0 = nl; } else { xf1 = xfv; nlv1 = nl; }
        }

#pragma unroll 2
        for (int p = 0; p < 16; ++p) {
            const f16x8 A1 = sm_a1[p * 64 + lane];
            const float* bp = &sm_b1p[(p * 2 + hi) * 16];   // broadcast (hi-only)
            const float* wp = &sm_w2p[(p * 2 + hi) * 16];
            const f32x4 b0 = *reinterpret_cast<const f32x4*>(bp);
            const f32x4 b1q = *reinterpret_cast<const f32x4*>(bp + 4);
            const f32x4 b2q = *reinterpret_cast<const f32x4*>(bp + 8);
            const f32x4 b3q = *reinterpret_cast<const f32x4*>(bp + 12);
            const f32x4 w0 = *reinterpret_cast<const f32x4*>(wp);
            const f32x4 w1q = *reinterpret_cast<const f32x4*>(wp + 4);
            const f32x4 w2q = *reinterpret_cast<const f32x4*>(wp + 8);
            const f32x4 w3q = *reinterpret_cast<const f32x4*>(wp + 12);
            f32x16 bC;
#pragma unroll
            for (int e = 0; e < 4; ++e) {
                bC[e] = b0[e]; bC[4 + e] = b1q[e]; bC[8 + e] = b2q[e]; bC[12 + e] = b3q[e];
            }
            // stage1: d[r] = h[p*32 + R(r,hi)] (bias via C) for b=c
            const f32x16 d0 = __builtin_amdgcn_mfma_f32_32x32x16_f16(A1, xf0, bC, 0, 0, 0);
            const f32x16 d1 = __builtin_amdgcn_mfma_f32_32x32x16_f16(A1, xf1, bC, 0, 0, 0);
            // stage2: FMAs with free |.| modifier
#pragma unroll
            for (int e = 0; e < 4; ++e) {
                nlv0[e] = fmaf(w0[e],  fabsf(d0[e]),      nlv0[e]);
                nlv0[e] = fmaf(w1q[e], fabsf(d0[4 + e]),  nlv0[e]);
                nlv0[e] = fmaf(w2q[e], fabsf(d0[8 + e]),  nlv0[e]);
                nlv0[e] = fmaf(w3q[e], fabsf(d0[12 + e]), nlv0[e]);
                nlv1[e] = fmaf(w0[e],  fabsf(d1[e]),      nlv1[e]);
                nlv1[e] = fmaf(w1q[e], fabsf(d1[4 + e]),  nlv1[e]);
                nlv1[e] = fmaf(w2q[e], fabsf(d1[8 + e]),  nlv1[e]);
                nlv1[e] = fmaf(w3q[e], fabsf(d1[12 + e]), nlv1[e]);
            }
        }

        // epilogue: lane and lane^32 hold complementary h-halves AND lin-halves
        {
            float s0 = nlv0[0] + nlv0[1] + nlv0[2] + nlv0[3];
            float s1 = nlv1[0] + nlv1[1] + nlv1[2] + nlv1[3];
            s0 += __shfl_xor(s0, 32, 64);
            s1 += __shfl_xor(s1, 32, 64);
            if (hi == 0) {
                out[(size_t)(rbase) * 16 + o]      = s0 + c0;
                out[(size_t)(rbase + 32) * 16 + o] = s1 + c0;
            }
        }
    }
}

extern "C" void kernel_launch(void* const* d_in, const int* in_sizes, int n_in,
                              void* d_out, int out_size, void* d_ws, size_t ws_size,
                              hipStream_t stream) {
    const float* x  = (const float*)d_in[0];
    const float* W1 = (const float*)d_in[1];
    const float* b1 = (const float*)d_in[2];
    const float* W2 = (const float*)d_in[3];
    const float* b2 = (const float*)d_in[4];
    float* out = (float*)d_out;

    mlp_fused<<<256, 1024, 0, stream>>>(x, W1, b1, W2, b2, out);
}